// Round 2
// baseline (307.220 us; speedup 1.0000x reference)
//
#include <hip/hip_runtime.h>

// NonLocalBlock3D fused pipeline v2:
//   proj3 (theta/phi row-major, g transposed) -> flash (KV-split 16, T12 reg
//   exchange for P, T14 async staging, T13 defer-max) -> merge_y -> final_proj.
// All matmuls bf16 MFMA v_mfma_f32_32x32x16_bf16; fp32 accumulate.
// Layouts (learn_hip m74/m101):
//   A-frag: lane holds A[l&31][8*(l>>5)+u]
//   B-frag: lane holds B[8*(l>>5)+u][l&31]
//   C/D:    col = l&31, row = (r&3) + 8*(r>>2) + 4*(l>>5)

typedef __bf16 bf16x8 __attribute__((ext_vector_type(8)));
typedef __bf16 bf16x4 __attribute__((ext_vector_type(4)));
typedef __bf16 bf16x2 __attribute__((ext_vector_type(2)));
typedef float f32x16 __attribute__((ext_vector_type(16)));

#define DEV __device__ __forceinline__

constexpr int NROW = 8192;   // N
constexpr int CDIM = 256;    // C
constexpr int DI   = 128;    // INTER
constexpr int KVS  = 16;     // kv splits for flash
constexpr int NIT  = NROW / KVS / 64;  // 8 tiles of 64 kv per split

DEV int crow(int r, int h) { return (r & 3) + 8 * (r >> 2) + 4 * h; }

DEV f32x16 mfma(bf16x8 a, bf16x8 b, f32x16 c) {
    return __builtin_amdgcn_mfma_f32_32x32x16_bf16(a, b, c, 0, 0, 0);
}

DEV unsigned pack2(float a, float b) {
    union { __bf16 h[2]; unsigned u; } t;
    t.h[0] = (__bf16)a; t.h[1] = (__bf16)b;
    return t.u;
}

// ---------------------------------------------------------------------------
// proj3: blockIdx.y in {0:theta, 1:phi} -> out[row][n] row-major bf16;
//        blockIdx.y == 2 (g)            -> outT[n][row] transposed bf16.
// x fp32 [8192][256], w fp32 [256][128].  grid (64,3), block 256 (4 waves).
// ---------------------------------------------------------------------------
__global__ __launch_bounds__(256, 2) void proj3(
    const float* __restrict__ x,
    const float* __restrict__ thw, const float* __restrict__ thb,
    const float* __restrict__ phw, const float* __restrict__ phb,
    const float* __restrict__ gw,  const float* __restrict__ gb,
    __bf16* __restrict__ qo, __bf16* __restrict__ ko, __bf16* __restrict__ vT)
{
    __shared__ __align__(16) __bf16 Wl[CDIM * DI];  // [256 k][128 n]
    const int which = blockIdx.y;
    const float* w    = which == 0 ? thw : which == 1 ? phw : gw;
    const float* bias = which == 0 ? thb : which == 1 ? phb : gb;

    const int tid = threadIdx.x;
    const int wv = tid >> 6, lane = tid & 63, l31 = lane & 31, h = lane >> 5;

#pragma unroll
    for (int j = 0; j < 32; ++j) {
        int cid = j * 256 + tid;                 // [0, 8192) float4s
        float4 v = ((const float4*)w)[cid];
        bf16x4 t;
        t[0] = (__bf16)v.x; t[1] = (__bf16)v.y; t[2] = (__bf16)v.z; t[3] = (__bf16)v.w;
        *(bf16x4*)(&Wl[cid * 4]) = t;
    }
    __syncthreads();

    if (which < 2) {
        __bf16* out = which == 0 ? qo : ko;
        const int row0 = blockIdx.x * 128 + wv * 32;
        f32x16 acc[4] = {};
#pragma unroll
        for (int kk = 0; kk < 16; ++kk) {
            const float4* xp = (const float4*)(x + (size_t)(row0 + l31) * CDIM + kk * 16 + h * 8);
            float4 a0 = xp[0], a1 = xp[1];
            bf16x8 af;
            af[0] = (__bf16)a0.x; af[1] = (__bf16)a0.y; af[2] = (__bf16)a0.z; af[3] = (__bf16)a0.w;
            af[4] = (__bf16)a1.x; af[5] = (__bf16)a1.y; af[6] = (__bf16)a1.z; af[7] = (__bf16)a1.w;
#pragma unroll
            for (int jn = 0; jn < 4; ++jn) {
                bf16x8 bf;
#pragma unroll
                for (int u = 0; u < 8; ++u)
                    bf[u] = Wl[(kk * 16 + h * 8 + u) * DI + jn * 32 + l31];
                acc[jn] = mfma(af, bf, acc[jn]);
            }
        }
#pragma unroll
        for (int jn = 0; jn < 4; ++jn) {
            int col = jn * 32 + l31;
            float bv = bias[col];
#pragma unroll
            for (int r = 0; r < 16; ++r)
                out[(size_t)(row0 + crow(r, h)) * DI + col] = (__bf16)(acc[jn][r] + bv);
        }
    } else {
        const int n0 = blockIdx.x * 128;   // x-row base
        f32x16 acc[4] = {};
#pragma unroll
        for (int kk = 0; kk < 16; ++kk) {
            bf16x8 af;
#pragma unroll
            for (int u = 0; u < 8; ++u)
                af[u] = Wl[(kk * 16 + h * 8 + u) * DI + wv * 32 + l31];
#pragma unroll
            for (int jn = 0; jn < 4; ++jn) {
                const float4* xp = (const float4*)(x + (size_t)(n0 + jn * 32 + l31) * CDIM + kk * 16 + h * 8);
                float4 b0 = xp[0], b1 = xp[1];
                bf16x8 bf;
                bf[0] = (__bf16)b0.x; bf[1] = (__bf16)b0.y; bf[2] = (__bf16)b0.z; bf[3] = (__bf16)b0.w;
                bf[4] = (__bf16)b1.x; bf[5] = (__bf16)b1.y; bf[6] = (__bf16)b1.z; bf[7] = (__bf16)b1.w;
                acc[jn] = mfma(af, bf, acc[jn]);
            }
        }
#pragma unroll
        for (int jn = 0; jn < 4; ++jn) {
            int xr = n0 + jn * 32 + l31;
#pragma unroll
            for (int r = 0; r < 16; ++r) {
                int i = wv * 32 + crow(r, h);
                vT[(size_t)i * NROW + xr] = (__bf16)(acc[jn][r] + bias[i]);
            }
        }
    }
}

// ---------------------------------------------------------------------------
// flash v2: online-softmax attention, swapped QK^T; P exchanged in-register
// (pack2 + shfl_xor(32)); T14 issue-early/write-late staging; T13 defer-max.
// grid (64 qtiles, 16 splits), block 256 (4 waves x 32 q-rows). LDS 32KB.
// ---------------------------------------------------------------------------
__global__ __launch_bounds__(256, 3) void flash(
    const __bf16* __restrict__ q, const __bf16* __restrict__ k,
    const __bf16* __restrict__ vT, __bf16* __restrict__ yaccT,
    float* __restrict__ mlm, float* __restrict__ mll)
{
    __shared__ __align__(16) __bf16 Kt[64 * 128];   // [kv][d], swz ^((kv&15)<<3)
    __shared__ __align__(16) __bf16 Vt[64 * 128];   // [d>>1][(d&1)*64+kv], swz ^((rw&15)<<3)

    const int tid = threadIdx.x;
    const int wv = tid >> 6, lane = tid & 63, l31 = lane & 31, h = lane >> 5;
    const int qt = blockIdx.x, sp = blockIdx.y;
    const int q0 = qt * 128 + wv * 32;

    bf16x8 qf[8];
#pragma unroll
    for (int kk = 0; kk < 8; ++kk)
        qf[kk] = *(const bf16x8*)(q + (size_t)(q0 + l31) * DI + kk * 16 + h * 8);

    f32x16 yacc[4] = {};
    float m = -1e30f, l = 0.f;

    bf16x8 kr[4], vr[4];
    // prologue: stage tile 0
    {
        const int kvb = sp * (NROW / KVS);
#pragma unroll
        for (int j = 0; j < 4; ++j) {
            int cid = j * 256 + tid, r = cid >> 4, dc = (cid & 15) * 8;
            kr[j] = *(const bf16x8*)(k + (size_t)(kvb + r) * DI + dc);
        }
#pragma unroll
        for (int j = 0; j < 4; ++j) {
            int cid = j * 256 + tid, d = cid >> 3, kvc = (cid & 7) * 8;
            vr[j] = *(const bf16x8*)(vT + (size_t)d * NROW + kvb + kvc);
        }
#pragma unroll
        for (int j = 0; j < 4; ++j) {
            int cid = j * 256 + tid, r = cid >> 4, dc = (cid & 15) * 8;
            *(bf16x8*)(&Kt[(r * 128 + dc) ^ ((r & 15) << 3)]) = kr[j];
        }
#pragma unroll
        for (int j = 0; j < 4; ++j) {
            int cid = j * 256 + tid, d = cid >> 3, kvc = (cid & 7) * 8;
            int rw = d >> 1, co = (d & 1) * 64 + kvc;
            *(bf16x8*)(&Vt[(rw * 128 + co) ^ ((rw & 15) << 3)]) = vr[j];
        }
    }
    __syncthreads();

    for (int it = 0; it < NIT; ++it) {
        // T14: issue next tile's global loads now; ds_write them after barrier
        const int kvb_n = sp * (NROW / KVS) + (it < NIT - 1 ? (it + 1) * 64 : it * 64);
#pragma unroll
        for (int j = 0; j < 4; ++j) {
            int cid = j * 256 + tid, r = cid >> 4, dc = (cid & 15) * 8;
            kr[j] = *(const bf16x8*)(k + (size_t)(kvb_n + r) * DI + dc);
        }
#pragma unroll
        for (int j = 0; j < 4; ++j) {
            int cid = j * 256 + tid, d = cid >> 3, kvc = (cid & 7) * 8;
            vr[j] = *(const bf16x8*)(vT + (size_t)d * NROW + kvb_n + kvc);
        }

        // S^T = K . Q^T
        f32x16 sacc[2] = {};
#pragma unroll
        for (int kk = 0; kk < 8; ++kk) {
#pragma unroll
            for (int jm = 0; jm < 2; ++jm) {
                int kv = jm * 32 + l31;
                bf16x8 kf = *(const bf16x8*)(&Kt[(kv * 128 + kk * 16 + h * 8) ^ ((kv & 15) << 3)]);
                sacc[jm] = mfma(kf, qf[kk], sacc[jm]);
            }
        }

        // online softmax (q-column l31; values split across h pair)
        float tm = -1e30f;
#pragma unroll
        for (int jm = 0; jm < 2; ++jm)
#pragma unroll
            for (int r = 0; r < 16; ++r) tm = fmaxf(tm, sacc[jm][r]);
        tm = fmaxf(tm, __shfl_xor(tm, 32));
        if (!__all(tm <= m + 8.f)) {           // T13 defer-max
            float mn = fmaxf(m, tm);
            float sc = __expf(m - mn);
            l *= sc;
#pragma unroll
            for (int jd = 0; jd < 4; ++jd) yacc[jd] *= sc;
            m = mn;
        }
        float ts = 0.f;
#pragma unroll
        for (int jm = 0; jm < 2; ++jm)
#pragma unroll
            for (int r = 0; r < 16; ++r) {
                float p = __expf(sacc[jm][r] - m);
                sacc[jm][r] = p;
                ts += p;
            }
        ts += __shfl_xor(ts, 32);
        l += ts;

        // T12: P -> bf16 fragments via pack + shfl_xor(32) (no LDS round-trip)
        bf16x8 pf[4];
#pragma unroll
        for (int ks = 0; ks < 4; ++ks) {
            const int jm = ks >> 1, r0 = 8 * (ks & 1);
            unsigned a0 = pack2(sacc[jm][r0],     sacc[jm][r0 + 1]);
            unsigned a1 = pack2(sacc[jm][r0 + 2], sacc[jm][r0 + 3]);
            unsigned b0 = pack2(sacc[jm][r0 + 4], sacc[jm][r0 + 5]);
            unsigned b1 = pack2(sacc[jm][r0 + 6], sacc[jm][r0 + 7]);
            unsigned snd0 = h ? a0 : b0, snd1 = h ? a1 : b1;
            unsigned loc0 = h ? b0 : a0, loc1 = h ? b1 : a1;
            unsigned rcv0 = (unsigned)__shfl_xor((int)snd0, 32);
            unsigned rcv1 = (unsigned)__shfl_xor((int)snd1, 32);
            union { unsigned w[4]; bf16x8 v; } pu;
            pu.w[0] = h ? rcv0 : loc0;
            pu.w[1] = h ? rcv1 : loc1;
            pu.w[2] = h ? loc0 : rcv0;
            pu.w[3] = h ? loc1 : rcv1;
            pf[ks] = pu.v;
        }

        // y^T += V^T . P^T
#pragma unroll
        for (int jd = 0; jd < 4; ++jd) {
            int d = jd * 32 + l31, rw = d >> 1;
#pragma unroll
            for (int ks = 0; ks < 4; ++ks) {
                int co = (d & 1) * 64 + ks * 16 + h * 8;
                bf16x8 vf = *(const bf16x8*)(&Vt[(rw * 128 + co) ^ ((rw & 15) << 3)]);
                yacc[jd] = mfma(vf, pf[ks], yacc[jd]);
            }
        }
        __syncthreads();

        if (it < NIT - 1) {
#pragma unroll
            for (int j = 0; j < 4; ++j) {
                int cid = j * 256 + tid, r = cid >> 4, dc = (cid & 15) * 8;
                *(bf16x8*)(&Kt[(r * 128 + dc) ^ ((r & 15) << 3)]) = kr[j];
            }
#pragma unroll
            for (int j = 0; j < 4; ++j) {
                int cid = j * 256 + tid, d = cid >> 3, kvc = (cid & 7) * 8;
                int rw = d >> 1, co = (d & 1) * 64 + kvc;
                *(bf16x8*)(&Vt[(rw * 128 + co) ^ ((rw & 15) << 3)]) = vr[j];
            }
        }
        __syncthreads();
    }

    // write unnormalized partials (bf16), transposed (coalesced along q)
#pragma unroll
    for (int jd = 0; jd < 4; ++jd)
#pragma unroll
        for (int r = 0; r < 16; ++r) {
            int d = jd * 32 + crow(r, h);
            yaccT[(size_t)sp * DI * NROW + (size_t)d * NROW + qt * 128 + wv * 32 + l31] =
                (__bf16)yacc[jd][r];
        }
    if (h == 0) {
        mlm[sp * NROW + q0 + l31] = m;
        mll[sp * NROW + q0 + l31] = l;
    }
}

// ---------------------------------------------------------------------------
// merge_y: combine KVS split partials -> y bf16 [8192][128]
// thread handles 2 consecutive q for one d (float2 / bf16x2 loads, coalesced)
// ---------------------------------------------------------------------------
__global__ void merge_y(const __bf16* __restrict__ yaccT,
                        const float* __restrict__ mlm, const float* __restrict__ mll,
                        __bf16* __restrict__ y)
{
    int idx = blockIdx.x * 256 + threadIdx.x;   // [0, 128*4096)
    int d = idx >> 12, q2 = (idx & 4095) * 2;
    float2 mv[KVS];
    float m0 = -1e30f, m1 = -1e30f;
#pragma unroll
    for (int s = 0; s < KVS; ++s) {
        mv[s] = *(const float2*)(mlm + s * NROW + q2);
        m0 = fmaxf(m0, mv[s].x); m1 = fmaxf(m1, mv[s].y);
    }
    float L0 = 0.f, L1 = 0.f, a0 = 0.f, a1 = 0.f;
#pragma unroll
    for (int s = 0; s < KVS; ++s) {
        float2 lv = *(const float2*)(mll + s * NROW + q2);
        float e0 = __expf(mv[s].x - m0), e1 = __expf(mv[s].y - m1);
        L0 += lv.x * e0; L1 += lv.y * e1;
        bf16x2 pv = *(const bf16x2*)(yaccT + (size_t)s * DI * NROW + (size_t)d * NROW + q2);
        a0 += e0 * (float)pv[0]; a1 += e1 * (float)pv[1];
    }
    y[(size_t)q2 * DI + d]       = (__bf16)(a0 / L0);
    y[(size_t)(q2 + 1) * DI + d] = (__bf16)(a1 / L1);
}

// ---------------------------------------------------------------------------
// final_proj: out[row][c] = y[row][:] @ W[:, c] + Wb[c] + x[row][c]  (fp32 out)
// grid 256 blocks x 32 rows; 4 waves split cols (64 each). W LDS 64KB.
// ---------------------------------------------------------------------------
__global__ __launch_bounds__(256, 2) void final_proj(
    const __bf16* __restrict__ y, const float* __restrict__ w,
    const float* __restrict__ bias, const float* __restrict__ x,
    float* __restrict__ out)
{
    __shared__ __align__(16) __bf16 Wl[DI * CDIM];  // [128 k][256 n]
    const int tid = threadIdx.x;
    const int wv = tid >> 6, lane = tid & 63, l31 = lane & 31, h = lane >> 5;

#pragma unroll
    for (int j = 0; j < 32; ++j) {
        int cid = j * 256 + tid;                // [0, 8192) float4s
        float4 v = ((const float4*)w)[cid];
        bf16x4 t;
        t[0] = (__bf16)v.x; t[1] = (__bf16)v.y; t[2] = (__bf16)v.z; t[3] = (__bf16)v.w;
        *(bf16x4*)(&Wl[cid * 4]) = t;
    }
    __syncthreads();

    const int row0 = blockIdx.x * 32;
    bf16x8 af[8];
#pragma unroll
    for (int kk = 0; kk < 8; ++kk)
        af[kk] = *(const bf16x8*)(y + (size_t)(row0 + l31) * DI + kk * 16 + h * 8);

    f32x16 acc[2] = {};
#pragma unroll
    for (int kk = 0; kk < 8; ++kk) {
#pragma unroll
        for (int jn = 0; jn < 2; ++jn) {
            int col0 = (wv * 2 + jn) * 32;
            bf16x8 bf;
#pragma unroll
            for (int u = 0; u < 8; ++u)
                bf[u] = Wl[(kk * 16 + h * 8 + u) * CDIM + col0 + l31];
            acc[jn] = mfma(af[kk], bf, acc[jn]);
        }
    }

#pragma unroll
    for (int jn = 0; jn < 2; ++jn) {
        int col = (wv * 2 + jn) * 32 + l31;
        float bv = bias[col];
#pragma unroll
        for (int r = 0; r < 16; ++r) {
            int row = row0 + crow(r, h);
            out[(size_t)row * CDIM + col] = acc[jn][r] + bv + x[(size_t)row * CDIM + col];
        }
    }
}

// ---------------------------------------------------------------------------
extern "C" void kernel_launch(void* const* d_in, const int* in_sizes, int n_in,
                              void* d_out, int out_size, void* d_ws, size_t ws_size,
                              hipStream_t stream)
{
    const float* x    = (const float*)d_in[0];
    const float* g_w  = (const float*)d_in[1];
    const float* g_b  = (const float*)d_in[2];
    const float* th_w = (const float*)d_in[3];
    const float* th_b = (const float*)d_in[4];
    const float* ph_w = (const float*)d_in[5];
    const float* ph_b = (const float*)d_in[6];
    const float* W_w  = (const float*)d_in[7];
    const float* W_b  = (const float*)d_in[8];
    float* out = (float*)d_out;

    char* ws = (char*)d_ws;
    __bf16* qws  = (__bf16*)(ws);                                // 2 MB  theta
    __bf16* kws  = (__bf16*)(ws + (2ull << 20));                 // 2 MB  phi
    __bf16* vTws = (__bf16*)(ws + (4ull << 20));                 // 2 MB  g^T
    __bf16* yws  = (__bf16*)(ws + (6ull << 20));                 // 2 MB  attn out
    float*  mlm  = (float*)(ws + (8ull << 20));                  // 512 KB
    float*  mll  = (float*)(ws + (8ull << 20) + (512ull << 10)); // 512 KB
    __bf16* yac  = (__bf16*)(ws + (9ull << 20));                 // 32 MB bf16 partials

    proj3<<<dim3(64, 3), 256, 0, stream>>>(x, th_w, th_b, ph_w, ph_b, g_w, g_b,
                                           qws, kws, vTws);
    flash<<<dim3(64, KVS), 256, 0, stream>>>(qws, kws, vTws, yac, mlm, mll);
    merge_y<<<2048, 256, 0, stream>>>(yac, mlm, mll, yws);
    final_proj<<<256, 256, 0, stream>>>(yws, W_w, W_b, x, out);
}

// Round 3
// 157.663 us; speedup vs baseline: 1.9486x; 1.9486x over previous
//
#include <hip/hip_runtime.h>

// NonLocalBlock3D fused pipeline v3:
//   prep_wT (transpose weights to bf16, L2-resident) ->
//   proj3 (no LDS, direct-global fragments) ->
//   flash (KV-split 8, fp32 full-line partials, LDS dbuf 1-barrier/iter,
//          T12 reg exchange, T13 defer-max, T5 setprio, XCD split pinning) ->
//   merge_y -> final_proj (no LDS).
// MFMA v_mfma_f32_32x32x16_bf16; layouts (m74/m101):
//   A-frag: lane holds A[l&31][8*(l>>5)+u]
//   B-frag: lane holds B[8*(l>>5)+u][l&31]
//   C/D:    col = l&31, row = (r&3) + 8*(r>>2) + 4*(l>>5)

typedef __bf16 bf16x8 __attribute__((ext_vector_type(8)));
typedef __bf16 bf16x4 __attribute__((ext_vector_type(4)));
typedef float f32x16 __attribute__((ext_vector_type(16)));

#define DEV __device__ __forceinline__

constexpr int NROW = 8192;   // N
constexpr int CDIM = 256;    // C
constexpr int DI   = 128;    // INTER
constexpr int KVS  = 8;      // kv splits for flash
constexpr int NIT  = NROW / KVS / 64;  // 16 tiles of 64 kv per split

DEV int crow(int r, int h) { return (r & 3) + 8 * (r >> 2) + 4 * h; }

DEV f32x16 mfma(bf16x8 a, bf16x8 b, f32x16 c) {
    return __builtin_amdgcn_mfma_f32_32x32x16_bf16(a, b, c, 0, 0, 0);
}

DEV unsigned pack2(float a, float b) {
    union { __bf16 h[2]; unsigned u; } t;
    t.h[0] = (__bf16)a; t.h[1] = (__bf16)b;
    return t.u;
}

// ---------------------------------------------------------------------------
// prep_wT: transpose the three [256][128] fp32 weights -> [128][256] bf16,
// and W_w [128][256] -> [256][128] bf16. grid (128,4), block 256.
// ---------------------------------------------------------------------------
__global__ void prep_wT(const float* __restrict__ thw, const float* __restrict__ phw,
                        const float* __restrict__ gw,  const float* __restrict__ Ww,
                        __bf16* __restrict__ thT, __bf16* __restrict__ phT,
                        __bf16* __restrict__ gT,  __bf16* __restrict__ WwT)
{
    const int m = blockIdx.y;
    const int o = blockIdx.x * 256 + threadIdx.x;    // [0, 32768)
    if (m < 3) {
        const float* in = m == 0 ? thw : m == 1 ? phw : gw;   // [256 k][128 n]
        __bf16* out = m == 0 ? thT : m == 1 ? phT : gT;       // [128 n][256 k]
        int n = o >> 8, kk = o & 255;
        out[o] = (__bf16)in[kk * DI + n];
    } else {
        int c = o >> 7, kk = o & 127;                 // WwT [256 c][128 k]
        WwT[o] = (__bf16)Ww[kk * CDIM + c];
    }
}

// ---------------------------------------------------------------------------
// proj3: blockIdx.y in {0:theta, 1:phi} -> out[row][n] row-major bf16;
//        blockIdx.y == 2 (g)            -> outT[n][row] transposed bf16.
// No LDS, no barrier: W fragments are direct bf16x8 loads from the
// pre-transposed wT [128 n][256 k] (64KB, L2-resident).
// ---------------------------------------------------------------------------
__global__ __launch_bounds__(256) void proj3(
    const float* __restrict__ x,
    const __bf16* __restrict__ thT, const float* __restrict__ thb,
    const __bf16* __restrict__ phT, const float* __restrict__ phb,
    const __bf16* __restrict__ gT,  const float* __restrict__ gb,
    __bf16* __restrict__ qo, __bf16* __restrict__ ko, __bf16* __restrict__ vT)
{
    const int which = blockIdx.y;
    const __bf16* wt  = which == 0 ? thT : which == 1 ? phT : gT;
    const float* bias = which == 0 ? thb : which == 1 ? phb : gb;

    const int tid = threadIdx.x;
    const int wv = tid >> 6, lane = tid & 63, l31 = lane & 31, h = lane >> 5;

    if (which < 2) {
        __bf16* out = which == 0 ? qo : ko;
        const int row0 = blockIdx.x * 128 + wv * 32;
        f32x16 acc[4] = {};
#pragma unroll
        for (int kk = 0; kk < 16; ++kk) {
            const float4* xp = (const float4*)(x + (size_t)(row0 + l31) * CDIM + kk * 16 + h * 8);
            float4 a0 = xp[0], a1 = xp[1];
            bf16x8 af;
            af[0] = (__bf16)a0.x; af[1] = (__bf16)a0.y; af[2] = (__bf16)a0.z; af[3] = (__bf16)a0.w;
            af[4] = (__bf16)a1.x; af[5] = (__bf16)a1.y; af[6] = (__bf16)a1.z; af[7] = (__bf16)a1.w;
#pragma unroll
            for (int jn = 0; jn < 4; ++jn) {
                bf16x8 bfr = *(const bf16x8*)(wt + (size_t)(jn * 32 + l31) * CDIM + kk * 16 + h * 8);
                acc[jn] = mfma(af, bfr, acc[jn]);
            }
        }
#pragma unroll
        for (int jn = 0; jn < 4; ++jn) {
            int col = jn * 32 + l31;
            float bv = bias[col];
#pragma unroll
            for (int r = 0; r < 16; ++r)
                out[(size_t)(row0 + crow(r, h)) * DI + col] = (__bf16)(acc[jn][r] + bv);
        }
    } else {
        const int n0 = blockIdx.x * 128;   // x-row base
        f32x16 acc[4] = {};
#pragma unroll
        for (int kk = 0; kk < 16; ++kk) {
            bf16x8 afr = *(const bf16x8*)(wt + (size_t)(wv * 32 + l31) * CDIM + kk * 16 + h * 8);
#pragma unroll
            for (int jn = 0; jn < 4; ++jn) {
                const float4* xp = (const float4*)(x + (size_t)(n0 + jn * 32 + l31) * CDIM + kk * 16 + h * 8);
                float4 b0 = xp[0], b1 = xp[1];
                bf16x8 bf;
                bf[0] = (__bf16)b0.x; bf[1] = (__bf16)b0.y; bf[2] = (__bf16)b0.z; bf[3] = (__bf16)b0.w;
                bf[4] = (__bf16)b1.x; bf[5] = (__bf16)b1.y; bf[6] = (__bf16)b1.z; bf[7] = (__bf16)b1.w;
                acc[jn] = mfma(afr, bf, acc[jn]);
            }
        }
#pragma unroll
        for (int jn = 0; jn < 4; ++jn) {
            int xr = n0 + jn * 32 + l31;
#pragma unroll
            for (int r = 0; r < 16; ++r) {
                int i = wv * 32 + crow(r, h);
                vT[(size_t)i * NROW + xr] = (__bf16)(acc[jn][r] + bias[i]);
            }
        }
    }
}

// ---------------------------------------------------------------------------
// flash v3: KV-split 8, XCD split pinning (sp = bid&7 -> one split per XCD L2),
// LDS double-buffer (64KB) with ONE barrier per iter, T14 issue-early loads,
// T12 in-register P exchange, T13 defer-max, T5 setprio. fp32 partials
// (full 128B line writes). grid 512, block 256 (4 waves x 32 q).
// ---------------------------------------------------------------------------
__global__ __launch_bounds__(256, 2) void flash(
    const __bf16* __restrict__ q, const __bf16* __restrict__ k,
    const __bf16* __restrict__ vT, float* __restrict__ yaccT,
    float* __restrict__ mlm, float* __restrict__ mll)
{
    __shared__ __align__(16) __bf16 KtA[2][64 * 128];  // [kv][d], swz ^((kv&15)<<3)
    __shared__ __align__(16) __bf16 VtA[2][64 * 128];  // [d>>1][(d&1)*64+kv], swz ^((rw&15)<<3)

    const int tid = threadIdx.x;
    const int wv = tid >> 6, lane = tid & 63, l31 = lane & 31, h = lane >> 5;
    const int bid = blockIdx.x;
    const int sp = bid & 7, qt = bid >> 3;     // XCD = bid%8 -> split pinned per XCD
    const int q0 = qt * 128 + wv * 32;
    const size_t kvbase = (size_t)sp * (NROW / KVS);

    bf16x8 qf[8];
#pragma unroll
    for (int kk = 0; kk < 8; ++kk)
        qf[kk] = *(const bf16x8*)(q + (size_t)(q0 + l31) * DI + kk * 16 + h * 8);

    f32x16 yacc[4] = {};
    float m = -1e30f, l = 0.f;

    bf16x8 kr[4], vr[4];
    // prologue: stage tile 0 into buf 0
    {
#pragma unroll
        for (int j = 0; j < 4; ++j) {
            int cid = j * 256 + tid, r = cid >> 4, dc = (cid & 15) * 8;
            kr[j] = *(const bf16x8*)(k + (kvbase + r) * DI + dc);
        }
#pragma unroll
        for (int j = 0; j < 4; ++j) {
            int cid = j * 256 + tid, d = cid >> 3, kvc = (cid & 7) * 8;
            vr[j] = *(const bf16x8*)(vT + (size_t)d * NROW + kvbase + kvc);
        }
#pragma unroll
        for (int j = 0; j < 4; ++j) {
            int cid = j * 256 + tid, r = cid >> 4, dc = (cid & 15) * 8;
            *(bf16x8*)(&KtA[0][(r * 128 + dc) ^ ((r & 15) << 3)]) = kr[j];
        }
#pragma unroll
        for (int j = 0; j < 4; ++j) {
            int cid = j * 256 + tid, d = cid >> 3, kvc = (cid & 7) * 8;
            int rw = d >> 1, co = (d & 1) * 64 + kvc;
            *(bf16x8*)(&VtA[0][(rw * 128 + co) ^ ((rw & 15) << 3)]) = vr[j];
        }
    }
    __syncthreads();

    for (int it = 0; it < NIT; ++it) {
        const __bf16* Kt = KtA[it & 1];
        const __bf16* Vt = VtA[it & 1];

        // T14: issue next tile's global loads before compute
        if (it < NIT - 1) {
            const size_t kvb_n = kvbase + (size_t)(it + 1) * 64;
#pragma unroll
            for (int j = 0; j < 4; ++j) {
                int cid = j * 256 + tid, r = cid >> 4, dc = (cid & 15) * 8;
                kr[j] = *(const bf16x8*)(k + (kvb_n + r) * DI + dc);
            }
#pragma unroll
            for (int j = 0; j < 4; ++j) {
                int cid = j * 256 + tid, d = cid >> 3, kvc = (cid & 7) * 8;
                vr[j] = *(const bf16x8*)(vT + (size_t)d * NROW + kvb_n + kvc);
            }
        }

        // S^T = K . Q^T
        f32x16 sacc[2] = {};
        __builtin_amdgcn_s_setprio(1);
#pragma unroll
        for (int kk = 0; kk < 8; ++kk) {
#pragma unroll
            for (int jm = 0; jm < 2; ++jm) {
                int kv = jm * 32 + l31;
                bf16x8 kf = *(const bf16x8*)(&Kt[(kv * 128 + kk * 16 + h * 8) ^ ((kv & 15) << 3)]);
                sacc[jm] = mfma(kf, qf[kk], sacc[jm]);
            }
        }
        __builtin_amdgcn_s_setprio(0);

        // online softmax (q-column l31; values split across h pair)
        float tm = -1e30f;
#pragma unroll
        for (int jm = 0; jm < 2; ++jm)
#pragma unroll
            for (int r = 0; r < 16; ++r) tm = fmaxf(tm, sacc[jm][r]);
        tm = fmaxf(tm, __shfl_xor(tm, 32));
        if (!__all(tm <= m + 8.f)) {           // T13 defer-max
            float mn = fmaxf(m, tm);
            float sc = __expf(m - mn);
            l *= sc;
#pragma unroll
            for (int jd = 0; jd < 4; ++jd) yacc[jd] *= sc;
            m = mn;
        }
        float ts = 0.f;
#pragma unroll
        for (int jm = 0; jm < 2; ++jm)
#pragma unroll
            for (int r = 0; r < 16; ++r) {
                float p = __expf(sacc[jm][r] - m);
                sacc[jm][r] = p;
                ts += p;
            }
        ts += __shfl_xor(ts, 32);
        l += ts;

        // T12: P -> bf16 fragments via pack + shfl_xor(32) (no LDS round-trip)
        bf16x8 pf[4];
#pragma unroll
        for (int ks = 0; ks < 4; ++ks) {
            const int jm = ks >> 1, r0 = 8 * (ks & 1);
            unsigned a0 = pack2(sacc[jm][r0],     sacc[jm][r0 + 1]);
            unsigned a1 = pack2(sacc[jm][r0 + 2], sacc[jm][r0 + 3]);
            unsigned b0 = pack2(sacc[jm][r0 + 4], sacc[jm][r0 + 5]);
            unsigned b1 = pack2(sacc[jm][r0 + 6], sacc[jm][r0 + 7]);
            unsigned snd0 = h ? a0 : b0, snd1 = h ? a1 : b1;
            unsigned loc0 = h ? b0 : a0, loc1 = h ? b1 : a1;
            unsigned rcv0 = (unsigned)__shfl_xor((int)snd0, 32);
            unsigned rcv1 = (unsigned)__shfl_xor((int)snd1, 32);
            union { unsigned w[4]; bf16x8 v; } pu;
            pu.w[0] = h ? rcv0 : loc0;
            pu.w[1] = h ? rcv1 : loc1;
            pu.w[2] = h ? loc0 : rcv0;
            pu.w[3] = h ? loc1 : rcv1;
            pf[ks] = pu.v;
        }

        // y^T += V^T . P^T
        __builtin_amdgcn_s_setprio(1);
#pragma unroll
        for (int jd = 0; jd < 4; ++jd) {
            int d = jd * 32 + l31, rw = d >> 1;
#pragma unroll
            for (int ks = 0; ks < 4; ++ks) {
                int co = (d & 1) * 64 + ks * 16 + h * 8;
                bf16x8 vf = *(const bf16x8*)(&Vt[(rw * 128 + co) ^ ((rw & 15) << 3)]);
                yacc[jd] = mfma(vf, pf[ks], yacc[jd]);
            }
        }
        __builtin_amdgcn_s_setprio(0);

        // write next tile into the other buffer (safe: single barrier/iter)
        if (it < NIT - 1) {
            __bf16* Ktn = KtA[(it + 1) & 1];
            __bf16* Vtn = VtA[(it + 1) & 1];
#pragma unroll
            for (int j = 0; j < 4; ++j) {
                int cid = j * 256 + tid, r = cid >> 4, dc = (cid & 15) * 8;
                *(bf16x8*)(&Ktn[(r * 128 + dc) ^ ((r & 15) << 3)]) = kr[j];
            }
#pragma unroll
            for (int j = 0; j < 4; ++j) {
                int cid = j * 256 + tid, d = cid >> 3, kvc = (cid & 7) * 8;
                int rw = d >> 1, co = (d & 1) * 64 + kvc;
                *(bf16x8*)(&Vtn[(rw * 128 + co) ^ ((rw & 15) << 3)]) = vr[j];
            }
        }
        __syncthreads();
    }

    // write unnormalized partials fp32 (full 128B lines), transposed
#pragma unroll
    for (int jd = 0; jd < 4; ++jd)
#pragma unroll
        for (int r = 0; r < 16; ++r) {
            int d = jd * 32 + crow(r, h);
            yaccT[(size_t)sp * DI * NROW + (size_t)d * NROW + qt * 128 + wv * 32 + l31] = yacc[jd][r];
        }
    if (h == 0) {
        mlm[sp * NROW + q0 + l31] = m;
        mll[sp * NROW + q0 + l31] = l;
    }
}

// ---------------------------------------------------------------------------
// merge_y: combine KVS split partials -> y bf16 [8192][128]
// thread handles 4 consecutive q for one d (float4 loads, coalesced)
// ---------------------------------------------------------------------------
__global__ void merge_y(const float* __restrict__ yaccT,
                        const float* __restrict__ mlm, const float* __restrict__ mll,
                        __bf16* __restrict__ y)
{
    int idx = blockIdx.x * 256 + threadIdx.x;   // [0, 128*2048)
    int d = idx >> 11, q4 = (idx & 2047) * 4;
    float4 mv[KVS];
    float m0 = -1e30f, m1 = -1e30f, m2 = -1e30f, m3 = -1e30f;
#pragma unroll
    for (int s = 0; s < KVS; ++s) {
        mv[s] = *(const float4*)(mlm + s * NROW + q4);
        m0 = fmaxf(m0, mv[s].x); m1 = fmaxf(m1, mv[s].y);
        m2 = fmaxf(m2, mv[s].z); m3 = fmaxf(m3, mv[s].w);
    }
    float L0 = 0.f, L1 = 0.f, L2 = 0.f, L3 = 0.f;
    float a0 = 0.f, a1 = 0.f, a2 = 0.f, a3 = 0.f;
#pragma unroll
    for (int s = 0; s < KVS; ++s) {
        float4 lv = *(const float4*)(mll + s * NROW + q4);
        float4 pv = *(const float4*)(yaccT + (size_t)s * DI * NROW + (size_t)d * NROW + q4);
        float e0 = __expf(mv[s].x - m0), e1 = __expf(mv[s].y - m1);
        float e2 = __expf(mv[s].z - m2), e3 = __expf(mv[s].w - m3);
        L0 += lv.x * e0; L1 += lv.y * e1; L2 += lv.z * e2; L3 += lv.w * e3;
        a0 += e0 * pv.x; a1 += e1 * pv.y; a2 += e2 * pv.z; a3 += e3 * pv.w;
    }
    y[(size_t)(q4 + 0) * DI + d] = (__bf16)(a0 / L0);
    y[(size_t)(q4 + 1) * DI + d] = (__bf16)(a1 / L1);
    y[(size_t)(q4 + 2) * DI + d] = (__bf16)(a2 / L2);
    y[(size_t)(q4 + 3) * DI + d] = (__bf16)(a3 / L3);
}

// ---------------------------------------------------------------------------
// final_proj: out[row][c] = y[row][:] @ W[:, c] + Wb[c] + x[row][c]  (fp32 out)
// No LDS: W fragments direct from WwT [256 c][128 k] bf16 (64KB, L2-hot).
// grid 256 blocks x 32 rows; 4 waves x 2 col-tiles.
// ---------------------------------------------------------------------------
__global__ __launch_bounds__(256) void final_proj(
    const __bf16* __restrict__ y, const __bf16* __restrict__ WwT,
    const float* __restrict__ bias, const float* __restrict__ x,
    float* __restrict__ out)
{
    const int tid = threadIdx.x;
    const int wv = tid >> 6, lane = tid & 63, l31 = lane & 31, h = lane >> 5;
    const int row0 = blockIdx.x * 32;

    bf16x8 af[8];
#pragma unroll
    for (int kk = 0; kk < 8; ++kk)
        af[kk] = *(const bf16x8*)(y + (size_t)(row0 + l31) * DI + kk * 16 + h * 8);

    f32x16 acc[2] = {};
#pragma unroll
    for (int kk = 0; kk < 8; ++kk) {
#pragma unroll
        for (int jn = 0; jn < 2; ++jn) {
            int col0 = (wv * 2 + jn) * 32;
            bf16x8 bfr = *(const bf16x8*)(WwT + (size_t)(col0 + l31) * DI + kk * 16 + h * 8);
            acc[jn] = mfma(af[kk], bfr, acc[jn]);
        }
    }

#pragma unroll
    for (int jn = 0; jn < 2; ++jn) {
        int col = (wv * 2 + jn) * 32 + l31;
        float bv = bias[col];
#pragma unroll
        for (int r = 0; r < 16; ++r) {
            int row = row0 + crow(r, h);
            out[(size_t)row * CDIM + col] = acc[jn][r] + bv + x[(size_t)row * CDIM + col];
        }
    }
}

// ---------------------------------------------------------------------------
extern "C" void kernel_launch(void* const* d_in, const int* in_sizes, int n_in,
                              void* d_out, int out_size, void* d_ws, size_t ws_size,
                              hipStream_t stream)
{
    const float* x    = (const float*)d_in[0];
    const float* g_w  = (const float*)d_in[1];
    const float* g_b  = (const float*)d_in[2];
    const float* th_w = (const float*)d_in[3];
    const float* th_b = (const float*)d_in[4];
    const float* ph_w = (const float*)d_in[5];
    const float* ph_b = (const float*)d_in[6];
    const float* W_w  = (const float*)d_in[7];
    const float* W_b  = (const float*)d_in[8];
    float* out = (float*)d_out;

    char* ws = (char*)d_ws;
    __bf16* qws  = (__bf16*)(ws);                                // 2 MB  theta
    __bf16* kws  = (__bf16*)(ws + (2ull << 20));                 // 2 MB  phi
    __bf16* vTws = (__bf16*)(ws + (4ull << 20));                 // 2 MB  g^T
    __bf16* yws  = (__bf16*)(ws + (6ull << 20));                 // 2 MB  attn out
    __bf16* thT  = (__bf16*)(ws + (8ull << 20));                 // 64 KB
    __bf16* phT  = (__bf16*)(ws + (8ull << 20) + (64ull << 10)); // 64 KB
    __bf16* gTw  = (__bf16*)(ws + (8ull << 20) + (128ull << 10));// 64 KB
    __bf16* WwT  = (__bf16*)(ws + (8ull << 20) + (192ull << 10));// 64 KB
    float*  mlm  = (float*)(ws + (8ull << 20) + (512ull << 10)); // 256 KB
    float*  mll  = (float*)(ws + (8ull << 20) + (768ull << 10)); // 256 KB
    float*  yac  = (float*)(ws + (9ull << 20));                  // 32 MB fp32 partials

    prep_wT<<<dim3(128, 4), 256, 0, stream>>>(th_w, ph_w, g_w, W_w, thT, phT, gTw, WwT);
    proj3<<<dim3(64, 3), 256, 0, stream>>>(x, thT, th_b, phT, ph_b, gTw, g_b,
                                           qws, kws, vTws);
    flash<<<512, 256, 0, stream>>>(qws, kws, vTws, yac, mlm, mll);
    merge_y<<<1024, 256, 0, stream>>>(yac, mlm, mll, yws);
    final_proj<<<256, 256, 0, stream>>>(yws, WwT, W_b, x, out);
}